// Round 1
// baseline (572.323 us; speedup 1.0000x reference)
//
#include <hip/hip_runtime.h>

#define HH   512
#define WW   512
#define CIN  16
#define COUT 16
#define KK   5

// Each thread: one (n,h) row position, 4 pixels (w, w+64, w+128, w+192),
// all 16 output channels. Block (64,4): tile = 256 wide x 4 tall.
// Grid (2, 128, 16) covers (w-tiles, h-tiles, n).
__global__ __launch_bounds__(256) void diag_conv_kernel(
    const float* __restrict__ x, const float* __restrict__ fw,
    float* __restrict__ out)
{
    const int tx = threadIdx.x;                 // 0..63
    const int ty = threadIdx.y;                 // 0..3
    const int n  = blockIdx.z;
    const int h  = blockIdx.y * 4 + ty;
    const int wbase = blockIdx.x * 256 + tx;    // pixels wbase + p*64

    float acc[COUT][4];
#pragma unroll
    for (int o = 0; o < COUT; ++o)
#pragma unroll
        for (int p = 0; p < 4; ++p) acc[o][p] = 0.f;

    const float* xn = x + (size_t)n * CIN * HH * WW;

#pragma unroll 2
    for (int i = 0; i < CIN; ++i) {
        const float* xi = xn + i * HH * WW;
#pragma unroll
        for (int d = -2; d <= 2; ++d) {
            const int  hh  = h + d;
            const bool hok = (unsigned)hh < (unsigned)HH;
            const int  hcl = hok ? hh : 0;          // safe address
            float v[4];
#pragma unroll
            for (int p = 0; p < 4; ++p) {
                const int  ww  = wbase + p * 64 + d;
                const bool ok  = hok && ((unsigned)ww < (unsigned)WW);
                const int  wcl = ((unsigned)ww < (unsigned)WW) ? ww : 0; // safe address
                const float t  = xi[hcl * WW + wcl];
                v[p] = ok ? t : 0.f;                 // branchless zero-pad
            }
#pragma unroll
            for (int o = 0; o < COUT; ++o) {
                const float wt = fw[(o * CIN + i) * KK + (d + 2)]; // uniform -> s_load
#pragma unroll
                for (int p = 0; p < 4; ++p)
                    acc[o][p] = fmaf(wt, v[p], acc[o][p]);
            }
        }
    }

    float* on = out + ((size_t)n * COUT) * (size_t)(HH * WW) + (size_t)h * WW + wbase;
#pragma unroll
    for (int o = 0; o < COUT; ++o) {
#pragma unroll
        for (int p = 0; p < 4; ++p)
            on[(size_t)o * (HH * WW) + p * 64] = acc[o][p];
    }
}

extern "C" void kernel_launch(void* const* d_in, const int* in_sizes, int n_in,
                              void* d_out, int out_size, void* d_ws, size_t ws_size,
                              hipStream_t stream) {
    const float* x  = (const float*)d_in[0];   // [16,16,512,512] fp32
    const float* fw = (const float*)d_in[1];   // [16,16,5] fp32
    float* out = (float*)d_out;                // [16,16,512,512] fp32

    dim3 block(64, 4, 1);
    dim3 grid(WW / 256, HH / 4, 16);
    hipLaunchKernelGGL(diag_conv_kernel, grid, block, 0, stream, x, fw, out);
}